// Round 3
// baseline (81.486 us; speedup 1.0000x reference)
//
#include <hip/hip_runtime.h>

// CARAFE: features [B=2, h=64, w=64, C0=256] f32, masks [B, H=128, W=128, 25] f32,
// k=5, group=1. Nearest-upsample (half-pixel, 2x) == Y//2.
// out[b,Y,X,c] = sum_{di,dj} M[b,Y,X,di*5+dj] * F[b, Y/2+di-2, X/2+dj-2, c] (zero pad).
//
// R7 (discriminator round): R5 minus the register cap.
//  - R6 post-mortem: LDS staging (halved L2 feat traffic, zero-VGPR in-flight
//    loads) was NEUTRAL vs R4 (79.9 vs 78.1). If the kernel were ~33us and
//    latency-bound, R6 should have been ~55us total. It wasn't. => The kernel
//    is likely already ~8-15us; dur_us is dominated by a ~65-70us harness
//    reset floor (256MiB ws poison 44.7us + out poison ~5.6us + dozens of
//    tiny restore dispatches).
//  - Remaining confound: R5 bundled channel-split (occupancy 4->8 waves/SIMD)
//    WITH __launch_bounds__(256,8) (64-VGPR cap -> spills -> +27us). This
//    round isolates the split: same 2048-block channel-split grid, NO
//    min-waves cap, compiler picks VGPRs (~90 -> ~5 waves/SIMD, no spill).
//  - Pre-committed decision rule: neutral (78+-2) => kernel is at its memory
//    floor under the harness floor; declare roofline next round. Improvement
//    (65-72) => keep pushing occupancy. Regression => revert to R4, declare.
//  - Structure per wave: 2 x-adjacent low-res pixels (2x4 output block),
//    5x6=30 tap-union float2 loads (512B/instr, coalesced), 400 FMAs,
//    acc = 16 VGPRs. Zero feature bytes duplicated by the channel split
//    (halves read disjoint channels). Mask reads duplicate x2 but are
//    wave-uniform s_loads on L2-resident data.
//  - XCD swizzle kept: 16 contiguous global rows per XCD; both channel halves
//    of a row band land on the same XCD (~1.3MB feat working set incl. halo
//    fits the 4MiB per-XCD L2).
//  - Body branchless wrt data (clamp + 0/1 scale); t<=4 / t>=1 guards are
//    compile-time after full unroll.

#define C0   256
#define HLO  64
#define WLO  64
#define HHI  128
#define WHI  128
#define K    5
#define KK   25

__global__ __launch_bounds__(256) void carafe_kernel(
    const float* __restrict__ feat,   // [B, 64, 64, 256]
    const float* __restrict__ mask,   // [B, 128, 128, 25]
    float* __restrict__ out)          // [B, 128, 128, 256]
{
    // --- scalar (wave-uniform) tile coordinates ---
    // bid bits: [2:0]=xcd slot, then i = bid>>3 with
    //   i[0]   = ch   (channel half)
    //   i[4:1] = rloc (row within this XCD's 16-row band)
    //   i[7:5] = xblk (x tile)
    const int wv   = __builtin_amdgcn_readfirstlane(threadIdx.x >> 6); // 0..3
    const int bid  = blockIdx.x;          // 0..2047
    const int xcd  = bid & 7;             // round-robin XCD slot (heuristic)
    const int i    = bid >> 3;            // 0..255
    const int ch   = i & 1;               // channel half 0/1
    const int rloc = (i >> 1) & 15;       // 0..15
    const int xblk = i >> 5;              // 0..7
    const int r    = xcd * 16 + rloc;     // global row 0..127 (contig per XCD)
    const int b    = r >> 6;
    const int y0   = r & 63;
    const int x0   = xblk * 8 + wv * 2;   // low-res col of first quad
    const int lane = threadIdx.x & 63;
    const int c    = ch * 128 + lane * 2; // per-lane channel offset (float2)

    const int Y0 = y0 * 2;
    const int X0 = x0 * 2;

    const float* fbase = feat + (size_t)b * HLO * WLO * C0;
    const float* mrow0 = mask + (size_t)((b * HHI + Y0) * WHI + X0) * KK;
    const float* mrow1 = mrow0 + WHI * KK;

    // acc[row][qq]: output pixel (Y0+row, X0+qq), 2 channels each.
    float2 acc[2][4];
    #pragma unroll
    for (int rr = 0; rr < 2; ++rr)
        #pragma unroll
        for (int qq = 0; qq < 4; ++qq)
            acc[rr][qq] = make_float2(0.f, 0.f);

    #pragma unroll
    for (int di = 0; di < K; ++di) {
        const int   y  = y0 + di - 2;
        const int   yc = min(max(y, 0), HLO - 1);
        const float vy = ((unsigned)y < (unsigned)HLO) ? 1.f : 0.f;
        #pragma unroll
        for (int t = 0; t < 6; ++t) {           // tap col x0 + t - 2
            const int   x  = x0 + t - 2;
            const int   xc = min(max(x, 0), WLO - 1);
            const float v  = ((unsigned)x < (unsigned)WLO) ? vy : 0.f;

            float2 f = *(const float2*)(fbase + (size_t)(yc * WLO + xc) * C0 + c);
            f.x *= v; f.y *= v;

            // quad 0 (out cols qq=0,1): dj = t, valid for t<=4  (compile-time)
            if (t <= 4) {
                const int p = di * K + t;
                #pragma unroll
                for (int rr = 0; rr < 2; ++rr) {
                    const float* mr = rr ? mrow1 : mrow0;
                    #pragma unroll
                    for (int qq = 0; qq < 2; ++qq) {
                        const float wgt = mr[qq * KK + p];
                        acc[rr][qq].x = fmaf(f.x, wgt, acc[rr][qq].x);
                        acc[rr][qq].y = fmaf(f.y, wgt, acc[rr][qq].y);
                    }
                }
            }
            // quad 1 (out cols qq=2,3): dj = t-1, valid for t>=1 (compile-time)
            if (t >= 1) {
                const int p = di * K + t - 1;
                #pragma unroll
                for (int rr = 0; rr < 2; ++rr) {
                    const float* mr = rr ? mrow1 : mrow0;
                    #pragma unroll
                    for (int qq = 2; qq < 4; ++qq) {
                        const float wgt = mr[qq * KK + p];
                        acc[rr][qq].x = fmaf(f.x, wgt, acc[rr][qq].x);
                        acc[rr][qq].y = fmaf(f.y, wgt, acc[rr][qq].y);
                    }
                }
            }
        }
    }

    float* ob = out + (size_t)((b * HHI + Y0) * WHI + X0) * C0 + c;
    #pragma unroll
    for (int rr = 0; rr < 2; ++rr)
        #pragma unroll
        for (int qq = 0; qq < 4; ++qq)
            *(float2*)(ob + (size_t)(rr * WHI + qq) * C0) = acc[rr][qq];
}

extern "C" void kernel_launch(void* const* d_in, const int* in_sizes, int n_in,
                              void* d_out, int out_size, void* d_ws, size_t ws_size,
                              hipStream_t stream) {
    const float* feat = (const float*)d_in[0];   // 2*64*64*256
    const float* mask = (const float*)d_in[1];   // 2*128*128*25
    float* out = (float*)d_out;                  // 2*128*128*256

    // 2 batches * 64 rows * 8 x-blocks * 2 channel-halves = 2048 blocks;
    // 4 waves/block, each wave = 2 low-res pixels x 128 channels.
    carafe_kernel<<<2048, 256, 0, stream>>>(feat, mask, out);
}